// Round 5
// baseline (299.409 us; speedup 1.0000x reference)
//
#include <hip/hip_runtime.h>

#define T_  512
#define H_  1024
#define HC  512

typedef short short8 __attribute__((ext_vector_type(8)));
typedef float f32x16 __attribute__((ext_vector_type(16)));

__device__ __forceinline__ unsigned short f2bf(float x) {
  unsigned u = __float_as_uint(x);
  u += 0x7FFFu + ((u >> 16) & 1u);   // RTNE
  return (unsigned short)(u >> 16);
}
__device__ __forceinline__ float bf2f(unsigned short h) {
  return __uint_as_float(((unsigned)h) << 16);
}
__device__ __forceinline__ unsigned cvtpk(float lo, float hi) {
  unsigned r;
  asm("v_cvt_pk_bf16_f32 %0, %1, %2" : "=v"(r) : "v"(lo), "v"(hi));
  return r;
}
__device__ __forceinline__ void gload_lds16(const void* g, void* l) {
  __builtin_amdgcn_global_load_lds((const __attribute__((address_space(1))) unsigned*)g,
                                   (__attribute__((address_space(3))) unsigned*)l, 16, 0, 0);
}

// ---------- w1 [1024 k][512 n] fp32 -> wsBn k-octet-major: [o=k/8][n][8 bf16] ----------
__global__ void conv_w1(const float* __restrict__ w1, unsigned short* __restrict__ w1b) {
  int idx = blockIdx.x * 256 + threadIdx.x;   // 65536 exact
  int n = idx & 511, o = idx >> 9;            // o 0..127
  const float* src = w1 + (size_t)(o * 8) * HC + n;
  float v[8];
  #pragma unroll
  for (int j = 0; j < 8; ++j) v[j] = src[j * HC];
  uint4 d;
  d.x = cvtpk(v[0], v[1]);
  d.y = cvtpk(v[2], v[3]);
  d.z = cvtpk(v[4], v[5]);
  d.w = cvtpk(v[6], v[7]);
  *(uint4*)(w1b + (size_t)idx * 8) = d;
}

// ---------- fused GEMM: BM=64, BN=512, BK=32, 8 waves, dbuf + counted vmcnt ----------
// buf p at p*36864: A [4 o][64 r]x16B = 4KB ; B at +4096: [4 kg][512 c]x16B = 32KB
__global__ __launch_bounds__(512, 4) void gemm1(
    const float* __restrict__ hs, const unsigned short* __restrict__ w1b,
    const float* __restrict__ b1, const float* __restrict__ w2,
    const float* __restrict__ b2, float* __restrict__ logits, float* __restrict__ wsE)
{
  __shared__ __align__(16) unsigned char smem[80128];
  const int tid  = threadIdx.x;
  const int lane = tid & 63;
  const int w    = tid >> 6;              // 0..7
  const int row0 = blockIdx.x * 64;

  f32x16 acc[2][2];
  #pragma unroll
  for (int m = 0; m < 2; ++m)
    #pragma unroll
    for (int n = 0; n < 2; ++n)
      #pragma unroll
      for (int e = 0; e < 16; ++e) acc[m][n][e] = 0.f;

  // A staging: thread -> (row, 4-float segment)
  const int ar   = tid >> 3;              // 0..63
  const int aseg = tid & 7;               // 0..7
  const float* aSrc = hs + (size_t)(row0 + ar) * H_ + aseg * 4;
  const int aoff = (aseg >> 1) * 1024 + ar * 16 + (aseg & 1) * 8;  // byte in A region

  // B staging: wave w -> kg = w>>1, halves by w&1
  const int bkg = w >> 1;
  const int bc1 = (w & 1) * 256;

  // ---- prologue: tile 0 ----
  {
    float4 av = *(const float4*)(aSrc);
    #pragma unroll
    for (int i = 0; i < 4; ++i) {
      int c0 = bc1 + i * 64;
      gload_lds16(w1b + ((size_t)bkg * 512 + c0 + lane) * 8,
                  smem + 4096 + ((bkg * 512 + c0) * 16));
    }
    uint2 ap;
    ap.x = cvtpk(av.x, av.y); ap.y = cvtpk(av.z, av.w);
    *(uint2*)(smem + aoff) = ap;
  }

  for (int kt = 0; kt < 31; ++kt) {
    const int cur = kt & 1, nxt = cur ^ 1;
    float4 av = *(const float4*)(aSrc + (kt + 1) * 32);
    {
      unsigned char* bb = smem + nxt * 36864 + 4096;
      int O = (kt + 1) * 4 + bkg;
      #pragma unroll
      for (int i = 0; i < 4; ++i) {
        int c0 = bc1 + i * 64;
        gload_lds16(w1b + ((size_t)O * 512 + c0 + lane) * 8, bb + ((bkg * 512 + c0) * 16));
      }
    }
    // drain B(kt) (keep 5 newest = A(kt+1)+B(kt+1) in flight); publish A ds_writes
    asm volatile("s_waitcnt vmcnt(5) lgkmcnt(0)" ::: "memory");
    __builtin_amdgcn_s_barrier();
    __builtin_amdgcn_sched_barrier(0);
    {
      const unsigned char* ab = smem + cur * 36864;
      const unsigned char* bb = ab + 4096;
      #pragma unroll
      for (int ks = 0; ks < 2; ++ks) {
        const int kg = ks * 2 + (lane >> 5);
        short8 aF[2], bF[2];
        #pragma unroll
        for (int m = 0; m < 2; ++m)
          aF[m] = *(const short8*)(ab + kg * 1024 + (m * 32 + (lane & 31)) * 16);
        #pragma unroll
        for (int n = 0; n < 2; ++n)
          bF[n] = *(const short8*)(bb + (kg * 512 + w * 64 + n * 32 + (lane & 31)) * 16);
        __builtin_amdgcn_s_setprio(1);
        #pragma unroll
        for (int m = 0; m < 2; ++m)
          #pragma unroll
          for (int n = 0; n < 2; ++n)
            acc[m][n] = __builtin_amdgcn_mfma_f32_32x32x16_bf16(aF[m], bF[n], acc[m][n], 0, 0, 0);
        __builtin_amdgcn_s_setprio(0);
      }
    }
    // pack + write A(kt+1)
    {
      uint2 ap;
      ap.x = cvtpk(av.x, av.y); ap.y = cvtpk(av.z, av.w);
      *(uint2*)(smem + nxt * 36864 + aoff) = ap;
    }
  }
  // ---- tail: tile 31 (buf 1) ----
  asm volatile("s_waitcnt vmcnt(0) lgkmcnt(0)" ::: "memory");
  __builtin_amdgcn_s_barrier();
  __builtin_amdgcn_sched_barrier(0);
  {
    const unsigned char* ab = smem + 36864;
    const unsigned char* bb = ab + 4096;
    #pragma unroll
    for (int ks = 0; ks < 2; ++ks) {
      const int kg = ks * 2 + (lane >> 5);
      short8 aF[2], bF[2];
      #pragma unroll
      for (int m = 0; m < 2; ++m)
        aF[m] = *(const short8*)(ab + kg * 1024 + (m * 32 + (lane & 31)) * 16);
      #pragma unroll
      for (int n = 0; n < 2; ++n)
        bF[n] = *(const short8*)(bb + (kg * 512 + w * 64 + n * 32 + (lane & 31)) * 16);
      #pragma unroll
      for (int m = 0; m < 2; ++m)
        #pragma unroll
        for (int n = 0; n < 2; ++n)
          acc[m][n] = __builtin_amdgcn_mfma_f32_32x32x16_bf16(aF[m], bF[n], acc[m][n], 0, 0, 0);
    }
  }
  __syncthreads();

  // ---- epilogue: x = relu(acc + b1) -> LDS X [512 col][64 row] bf16, XOR-swizzled ----
  float b1v[2];
  #pragma unroll
  for (int n = 0; n < 2; ++n) b1v[n] = b1[w * 64 + n * 32 + (lane & 31)];

  #pragma unroll
  for (int m = 0; m < 2; ++m)
    #pragma unroll
    for (int n = 0; n < 2; ++n) {
      int col = w * 64 + n * 32 + (lane & 31);
      int csw = col & 7;
      unsigned char* cbase = smem + col * 128 + (lane >> 5) * 8;
      #pragma unroll
      for (int q = 0; q < 4; ++q) {
        float v0 = fmaxf(acc[m][n][q * 4 + 0] + b1v[n], 0.f);
        float v1 = fmaxf(acc[m][n][q * 4 + 1] + b1v[n], 0.f);
        float v2 = fmaxf(acc[m][n][q * 4 + 2] + b1v[n], 0.f);
        float v3 = fmaxf(acc[m][n][q * 4 + 3] + b1v[n], 0.f);
        uint2 d;
        d.x = cvtpk(v0, v1);
        d.y = cvtpk(v2, v3);
        *(uint2*)(cbase + (((4 * m + q) ^ csw) * 16)) = d;
      }
    }

  // W2 -> LDS bf16 [512][12], zero sAcc
  unsigned short* ldsW2 = (unsigned short*)(smem + 65536);
  float* sAcc = (float*)(smem + 77824);   // [64][9]
  {
    int cc = tid;   // one col per thread
    #pragma unroll
    for (int l = 0; l < 9; ++l) ldsW2[cc * 12 + l] = f2bf(w2[cc * 9 + l]);
    for (int i = tid; i < 576; i += 512) sAcc[i] = 0.f;
  }
  __syncthreads();

  // partial x@W2 per (row, col-chunk)
  {
    int r = tid & 63, ch = tid >> 6;      // 8 chunks of 64 cols
    int rblk = r >> 3, rlow = r & 7;
    float s[9];
    #pragma unroll
    for (int l = 0; l < 9; ++l) s[l] = 0.f;
    for (int c = ch * 64; c < ch * 64 + 64; ++c) {
      float xv = bf2f(*(const unsigned short*)(smem + c * 128 + ((rblk ^ (c & 7)) * 16) + rlow * 2));
      uint2 wa = *(const uint2*)(ldsW2 + c * 12);
      uint2 wb = *(const uint2*)(ldsW2 + c * 12 + 4);
      unsigned wcv = *(const unsigned*)(ldsW2 + c * 12 + 8);
      s[0] = fmaf(xv, __uint_as_float(wa.x << 16), s[0]);
      s[1] = fmaf(xv, __uint_as_float(wa.x & 0xFFFF0000u), s[1]);
      s[2] = fmaf(xv, __uint_as_float(wa.y << 16), s[2]);
      s[3] = fmaf(xv, __uint_as_float(wa.y & 0xFFFF0000u), s[3]);
      s[4] = fmaf(xv, __uint_as_float(wb.x << 16), s[4]);
      s[5] = fmaf(xv, __uint_as_float(wb.x & 0xFFFF0000u), s[5]);
      s[6] = fmaf(xv, __uint_as_float(wb.y << 16), s[6]);
      s[7] = fmaf(xv, __uint_as_float(wb.y & 0xFFFF0000u), s[7]);
      s[8] = fmaf(xv, __uint_as_float(wcv << 16), s[8]);
    }
    #pragma unroll
    for (int l = 0; l < 9; ++l) atomicAdd(&sAcc[r * 9 + l], s[l]);
  }
  __syncthreads();

  // finalize: +b2, write logits and wsE (exp, transposed [t][j][b])
  {
    int bb = row0 >> 9, t0g = row0 & 511;
    for (int v = tid; v < 576; v += 512) {
      int r = v / 9, l = v - r * 9;
      float val = sAcc[v] + b2[l];
      logits[(size_t)(row0 + r) * 9 + l] = val;
      wsE[(size_t)((t0g + r) * 9 + l) * 64 + bb] = __expf(val);
    }
  }
}

// ---------- CRF chunk matrices: 128 chunks x 4 steps, exp-domain with rescale ----------
#define NCH 128
#define CHL 4
__global__ __launch_bounds__(64, 1) void crf_chunks(
    const float* __restrict__ wsE, const int* __restrict__ labels,
    const int* __restrict__ amask, const float* __restrict__ logits,
    const float* __restrict__ trans, float* __restrict__ wsG)
{
  __shared__ float sT[81];
  int b = threadIdx.x;
  for (int i = b; i < 81; i += 64) sT[i] = trans[i];
  __syncthreads();
  int c = blockIdx.x;

  float eT[81];
  #pragma unroll
  for (int i = 0; i < 81; ++i) eT[i] = __expf(sT[i]);

  float G[81];
  #pragma unroll
  for (int i = 0; i < 9; ++i)
    #pragma unroll
    for (int j = 0; j < 9; ++j) G[i * 9 + j] = (i == j) ? 1.f : 0.f;

  float logC = 0.f, sumN = 0.f;
  int ft = -1, lt = -1, prevL = -1;

  int tstart = (c == 0) ? 1 : c * CHL;
  int tend = c * CHL + CHL;

  for (int t = tstart; t < tend; ++t) {
    int lab = labels[b * T_ + t];
    int am  = amask[b * T_ + t];
    bool valid = (lab != -100);
    int tag = valid ? lab : 0;
    bool m = (am != 0) && valid;

    float E[9];
    #pragma unroll
    for (int j = 0; j < 9; ++j) E[j] = wsE[(size_t)(t * 9 + j) * 64 + b];

    float emis = logits[(size_t)b * (T_ * 9) + t * 9 + tag];
    int pidx = (prevL < 0 ? 0 : prevL) * 9 + tag;
    float trTerm = (prevL >= 0) ? sT[pidx] : 0.f;
    sumN += m ? (emis + trTerm) : 0.f;
    ft = (m && ft < 0) ? tag : ft;
    lt = m ? tag : lt;
    prevL = m ? tag : prevL;

    #pragma unroll
    for (int i = 0; i < 9; ++i) {
      float nG[9];
      #pragma unroll
      for (int j = 0; j < 9; ++j) {
        float s = G[i * 9 + 0] * eT[j];
        #pragma unroll
        for (int k = 1; k < 9; ++k) s = fmaf(G[i * 9 + k], eT[k * 9 + j], s);
        nG[j] = s * E[j];
      }
      #pragma unroll
      for (int j = 0; j < 9; ++j) G[i * 9 + j] = m ? nG[j] : G[i * 9 + j];
    }
    float mx = G[0];
    #pragma unroll
    for (int e = 1; e < 81; ++e) mx = fmaxf(mx, G[e]);
    float rv = 1.0f / mx;
    logC += __logf(mx);
    #pragma unroll
    for (int e = 0; e < 81; ++e) G[e] *= rv;
  }

  float* o = wsG + (size_t)c * 88 * 64 + b;
  #pragma unroll
  for (int e = 0; e < 81; ++e) o[e * 64] = G[e];
  o[81 * 64] = logC;
  o[82 * 64] = sumN;
  o[83 * 64] = __int_as_float(ft);
  o[84 * 64] = __int_as_float(lt);
}

// ---------- fold level 1: 16 blocks, each folds 8 chunk matrices ----------
__global__ __launch_bounds__(64, 1) void crf_fold(
    const float* __restrict__ wsG, const float* __restrict__ trans,
    float* __restrict__ wsG2)
{
  __shared__ float sT[81];
  int b = threadIdx.x;
  for (int i = b; i < 81; i += 64) sT[i] = trans[i];
  __syncthreads();
  int f = blockIdx.x;

  float G[81];
  #pragma unroll
  for (int i = 0; i < 9; ++i)
    #pragma unroll
    for (int j = 0; j < 9; ++j) G[i * 9 + j] = (i == j) ? 1.f : 0.f;
  float logC = 0.f, sumN = 0.f;
  int ft = -1, lt = -1;

  for (int cc = 0; cc < 8; ++cc) {
    const float* g = wsG + (size_t)(f * 8 + cc) * 88 * 64 + b;
    float Gm[81];
    #pragma unroll
    for (int e = 0; e < 81; ++e) Gm[e] = g[e * 64];
    float lC = g[81 * 64], sN = g[82 * 64];
    int fte = __float_as_int(g[83 * 64]);
    int lte = __float_as_int(g[84 * 64]);

    #pragma unroll
    for (int i = 0; i < 9; ++i) {
      float row[9];
      #pragma unroll
      for (int j = 0; j < 9; ++j) {
        float s = G[i * 9 + 0] * Gm[j];
        #pragma unroll
        for (int k = 1; k < 9; ++k) s = fmaf(G[i * 9 + k], Gm[k * 9 + j], s);
        row[j] = s;
      }
      #pragma unroll
      for (int j = 0; j < 9; ++j) G[i * 9 + j] = row[j];
    }
    float mx = G[0];
    #pragma unroll
    for (int e = 1; e < 81; ++e) mx = fmaxf(mx, G[e]);
    logC += lC + __logf(mx);
    float rv = 1.0f / mx;
    #pragma unroll
    for (int e = 0; e < 81; ++e) G[e] *= rv;

    if (fte >= 0) {
      sumN += sN + (lt >= 0 ? sT[lt * 9 + fte] : 0.f);
      if (ft < 0) ft = fte;
      lt = lte;
    }
  }

  float* o = wsG2 + (size_t)f * 88 * 64 + b;
  #pragma unroll
  for (int e = 0; e < 81; ++e) o[e * 64] = G[e];
  o[81 * 64] = logC;
  o[82 * 64] = sumN;
  o[83 * 64] = __int_as_float(ft);
  o[84 * 64] = __int_as_float(lt);
}

// ---------- final: fold 16 + start/end + loss ----------
__global__ __launch_bounds__(64, 1) void crf_final(
    const float* __restrict__ wsE, const int* __restrict__ labels,
    const float* __restrict__ logits,
    const float* __restrict__ start_t, const float* __restrict__ end_t,
    const float* __restrict__ trans, const float* __restrict__ wsG2,
    float* __restrict__ out_loss)
{
  __shared__ float sT[81];
  int b = threadIdx.x;
  for (int i = b; i < 81; i += 64) sT[i] = trans[i];
  __syncthreads();

  int lab0 = labels[b * T_];
  int tag0 = (lab0 != -100) ? lab0 : 0;
  float num = start_t[tag0] + logits[(size_t)b * (T_ * 9) + tag0];
  int prev = tag0;

  float P[9];
  #pragma unroll
  for (int j = 0; j < 9; ++j) P[j] = __expf(start_t[j]) * wsE[j * 64 + b];
  float mx = P[0];
  #pragma unroll
  for (int j = 1; j < 9; ++j) mx = fmaxf(mx, P[j]);
  float C = __logf(mx);
  float rv = 1.0f / mx;
  #pragma unroll
  for (int j = 0; j < 9; ++j) P[j] *= rv;

  for (int c = 0; c < 16; ++c) {
    const float* g = wsG2 + (size_t)c * 88 * 64 + b;
    float Gm[81];
    #pragma unroll
    for (int e = 0; e < 81; ++e) Gm[e] = g[e * 64];
    float logC = g[81 * 64];
    float sumN = g[82 * 64];
    int ft = __float_as_int(g[83 * 64]);
    int lt = __float_as_int(g[84 * 64]);

    float nP[9];
    #pragma unroll
    for (int j = 0; j < 9; ++j) {
      float s = P[0] * Gm[j];
      #pragma unroll
      for (int i = 1; i < 9; ++i) s = fmaf(P[i], Gm[i * 9 + j], s);
      nP[j] = s;
    }
    float mxs = nP[0];
    #pragma unroll
    for (int j = 1; j < 9; ++j) mxs = fmaxf(mxs, nP[j]);
    float rvs = 1.0f / mxs;
    C += logC + __logf(mxs);
    #pragma unroll
    for (int j = 0; j < 9; ++j) P[j] = nP[j] * rvs;

    if (ft >= 0) {
      num += sumN + sT[prev * 9 + ft];
      prev = lt;
    }
  }

  float sfin = 0.f;
  #pragma unroll
  for (int j = 0; j < 9; ++j) sfin = fmaf(P[j], __expf(end_t[j]), sfin);
  float den = C + __logf(sfin);
  num += end_t[prev];
  float d = num - den;
  #pragma unroll
  for (int off = 32; off > 0; off >>= 1) d += __shfl_down(d, off);
  if (b == 0) out_loss[0] = -d * (1.0f / 64.0f);
}

extern "C" void kernel_launch(void* const* d_in, const int* in_sizes, int n_in,
                              void* d_out, int out_size, void* d_ws, size_t ws_size,
                              hipStream_t stream) {
  (void)in_sizes; (void)n_in; (void)out_size; (void)ws_size;
  const float* hs     = (const float*)d_in[0];
  const int*   am     = (const int*)  d_in[1];
  const int*   labels = (const int*)  d_in[2];
  const float* w1     = (const float*)d_in[3];
  const float* b1     = (const float*)d_in[4];
  const float* w2     = (const float*)d_in[5];
  const float* b2     = (const float*)d_in[6];
  const float* st     = (const float*)d_in[7];
  const float* en     = (const float*)d_in[8];
  const float* tr     = (const float*)d_in[9];
  float* out = (float*)d_out;

  unsigned short* wsBn = (unsigned short*)d_ws;                     // 1 MB
  float*          wsE  = (float*)((char*)d_ws + 1048576);           // 1.18 MB
  float*          wsG  = (float*)((char*)d_ws + 2228224);           // 2.88 MB (128*88*64*4)
  float*          wsG2 = (float*)((char*)d_ws + 5111808);           // 360 KB  (16*88*64*4)

  conv_w1   <<<256, 256, 0, stream>>>(w1, wsBn);
  gemm1     <<<512, 512, 0, stream>>>(hs, wsBn, b1, w2, b2, out, wsE);
  crf_chunks<<<128, 64,  0, stream>>>(wsE, labels, am, out, tr, wsG);
  crf_fold  <<<16,  64,  0, stream>>>(wsG, tr, wsG2);
  crf_final <<<1,   64,  0, stream>>>(wsE, labels, out, st, en, tr, wsG2, out + 294912);
}